// Round 6
// baseline (583.710 us; speedup 1.0000x reference)
//
#include <hip/hip_runtime.h>
#include <cstdint>

using bf16x8 = __attribute__((ext_vector_type(8))) __bf16;
using f32x4  = __attribute__((ext_vector_type(4))) float;
using s16x8  = __attribute__((ext_vector_type(8))) short;
using s16x4  = __attribute__((ext_vector_type(4))) short;

#define DI static __device__ __forceinline__

#define SB __builtin_amdgcn_sched_barrier(0)
#define VMCNT(n) do { asm volatile("s_waitcnt vmcnt(" #n ")" ::: "memory"); SB; } while (0)
#define LGKM0    do { asm volatile("s_waitcnt lgkmcnt(0)" ::: "memory"); SB; } while (0)
#define BAR      do { SB; __builtin_amdgcn_s_barrier(); SB; } while (0)

DI short f2bf(float f) {
  unsigned u = __float_as_uint(f);
  u = (u + 0x7fffu + ((u >> 16) & 1u)) >> 16;
  return (short)u;
}
DI float bf2f(short s) {
  return __uint_as_float(((unsigned)(unsigned short)s) << 16);
}

DI void gload16(const short* g, short* l) {
  __builtin_amdgcn_global_load_lds((const __attribute__((address_space(1))) unsigned*)g,
                                   (__attribute__((address_space(3))) unsigned*)l, 16, 0, 0);
}

DI f32x4 mfma16(bf16x8 a, bf16x8 b, f32x4 c) {
  return __builtin_amdgcn_mfma_f32_16x16x32_bf16(a, b, c, 0, 0, 0);
}

// Stage a [256 rows x 32 k] bf16 panel (16 KB) into LDS, XOR-swizzled.
template<int CALLS>
DI void stageW(const short* __restrict__ W, int rs, int koff, short* dst, int w, int lane) {
  #pragma unroll
  for (int i = 0; i < CALLS; ++i) {
    int idx = (w * CALLS + i) * 64 + lane;
    int row = idx >> 2, slot = idx & 3;
    gload16(W + (size_t)row * rs + koff + (slot ^ ((row ^ (row >> 2)) & 3)) * 8,
            dst + (w * CALLS + i) * 512);
  }
}

// ---------------- weight prep ----------------
__global__ void k_transpose(const float* __restrict__ src, short* __restrict__ dst,
                            int K, int N) {
  int idx = blockIdx.x * 256 + threadIdx.x;   // dst[n][k] = src[k][n]
  if (idx >= N * K) return;
  int n = idx / K, k = idx - n * K;
  dst[idx] = f2bf(src[(size_t)k * N + n]);
}

__global__ void k_prep_qkv(const float* __restrict__ w, const float* __restrict__ b,
                           short* __restrict__ wt, float* __restrict__ bp) {
  int idx = blockIdx.x * 256 + threadIdx.x;   // 768*256
  if (idx >= 768 * 256) return;
  int jn = idx >> 8;        // new col: q*256 + h*32 + d
  int k  = idx & 255;
  int q = jn >> 8, rest = jn & 255, h = rest >> 5, d = rest & 31;
  int jo = h * 96 + d * 3 + q;
  wt[idx] = f2bf(w[(size_t)k * 768 + jo]);
  if (k == 0) bp[jn] = b[jo];
}

// ---------------- QKV: fused LN1 + window gather + staged-weight GEMM ----------------
__global__ __launch_bounds__(256, 2) void k_qkvln(
    const float* __restrict__ x, const float* __restrict__ g1, const float* __restrict__ b1v,
    const short* __restrict__ WqkvT, const float* __restrict__ qbp,
    short* __restrict__ qkv, int win0, int mtot)
{
  __shared__ __align__(16) short As[64 * 256];      // 32 KB
  __shared__ __align__(16) short Ws[2][256 * 32];   // 2 x 16 KB
  const int tid = threadIdx.x, lane = tid & 63, w = tid >> 6;
  const int l15 = lane & 15, hi = lane >> 4, hi4 = hi * 4;
  const int wg = win0 + blockIdx.x;
  const int bb = wg >> 6, wl = wg & 63, wrr = wl >> 3, wcc = wl & 7;
  stageW<4>(WqkvT, 256, 0, &Ws[0][0], w, lane);     // seq0
  // LN1 + window gather -> As (swizzled)
  #pragma unroll
  for (int p = 0; p < 4; ++p) {
    int tok = w * 16 + p * 4 + hi;
    int sr = bb * 4096 + ((tok >> 3) * 8 + wrr) * 64 + (tok & 7) * 8 + wcc;
    const float* xr = x + (size_t)sr * 256;
    float4 v[4];
    #pragma unroll
    for (int ii = 0; ii < 4; ++ii) v[ii] = *(const float4*)(xr + l15 * 4 + ii * 64);
    float s = 0.f, q = 0.f;
    #pragma unroll
    for (int ii = 0; ii < 4; ++ii) {
      s += v[ii].x + v[ii].y + v[ii].z + v[ii].w;
      q += v[ii].x * v[ii].x + v[ii].y * v[ii].y + v[ii].z * v[ii].z + v[ii].w * v[ii].w;
    }
    #pragma unroll
    for (int mk = 1; mk < 16; mk <<= 1) { s += __shfl_xor(s, mk); q += __shfl_xor(q, mk); }
    float mean = s * (1.f / 256.f);
    float var  = q * (1.f / 256.f) - mean * mean;
    float rstd = rsqrtf(var + 1e-5f);
    #pragma unroll
    for (int ii = 0; ii < 4; ++ii) {
      float4 gv = *(const float4*)(g1 + l15 * 4 + ii * 64);
      float4 bv = *(const float4*)(b1v + l15 * 4 + ii * 64);
      s16x4 o;
      o[0] = f2bf((v[ii].x - mean) * rstd * gv.x + bv.x);
      o[1] = f2bf((v[ii].y - mean) * rstd * gv.y + bv.y);
      o[2] = f2bf((v[ii].z - mean) * rstd * gv.z + bv.z);
      o[3] = f2bf((v[ii].w - mean) * rstd * gv.w + bv.w);
      int c8 = (l15 >> 1) + ii * 8;
      *(s16x4*)(As + tok * 256 + ((c8 ^ (tok & 7)) << 3) + (l15 & 1) * 4) = o;
    }
  }
  LGKM0;
  BAR;            // As visible to all waves (seq0 landing checked at step0)
  int cur = 0;
  for (int p = 0; p < 3; ++p) {
    f32x4 acc[4][4] = {};
    for (int s = 0; s < 8; ++s) {
      int nseq = p * 8 + s + 1; if (nseq >= 24) nseq = 0;
      stageW<4>(WqkvT + (size_t)(nseq >> 3) * 65536, 256, (nseq & 7) * 32,
                &Ws[cur ^ 1][0], w, lane);
      VMCNT(4);
      BAR;        // B1: all waves' seq_s landed
      bf16x8 af[4], wf[4];
      #pragma unroll
      for (int m = 0; m < 4; ++m) {
        int row = m * 16 + l15;
        af[m] = *(const bf16x8*)(As + row * 256 + (((s * 4 + hi) ^ (row & 7)) << 3));
      }
      #pragma unroll
      for (int n = 0; n < 4; ++n) {
        int rc = w * 64 + n * 16 + l15;
        wf[n] = *(const bf16x8*)(&Ws[cur][0] + rc * 32 + ((hi ^ ((rc ^ (rc >> 2)) & 3)) << 3));
      }
      __builtin_amdgcn_s_setprio(1);
      #pragma unroll
      for (int m = 0; m < 4; ++m)
        #pragma unroll
        for (int n = 0; n < 4; ++n) acc[m][n] = mfma16(wf[n], af[m], acc[m][n]);
      __builtin_amdgcn_s_setprio(0);
      LGKM0;
      BAR;        // B2: buf free for overwrite
      cur ^= 1;
    }
    const float sc = (p == 0) ? 0.17677669529663687f : 1.0f;
    short* dst = qkv + ((size_t)p * mtot + (size_t)blockIdx.x * 64) * 256;
    #pragma unroll
    for (int n = 0; n < 4; ++n) {
      int colg = w * 64 + n * 16 + hi4;
      float4 bbv = *(const float4*)(qbp + p * 256 + colg);
      #pragma unroll
      for (int m = 0; m < 4; ++m) {
        int row = m * 16 + l15;
        s16x4 o;
        o[0] = f2bf((acc[m][n][0] + bbv.x) * sc);
        o[1] = f2bf((acc[m][n][1] + bbv.y) * sc);
        o[2] = f2bf((acc[m][n][2] + bbv.z) * sc);
        o[3] = f2bf((acc[m][n][3] + bbv.w) * sc);
        *(s16x4*)(dst + (size_t)row * 256 + colg) = o;
      }
    }
  }
}

// ---------------- window attention (unchanged) ----------------
__global__ __launch_bounds__(256, 4) void k_attn(
    const short* __restrict__ Q, const short* __restrict__ Kb,
    const short* __restrict__ V, short* __restrict__ O)
{
  __shared__ __align__(16) short Ks[64 * 72];
  __shared__ __align__(16) short VT[32 * 72];
  __shared__ __align__(16) short Ps[64 * 72];
  const int head = blockIdx.x & 7, win = blockIdx.x >> 3;
  const int tid = threadIdx.x, lane = tid & 63, w = tid >> 6;
  const int l15 = lane & 15, hi = lane >> 4, hi4 = hi * 4;
  const size_t base = (size_t)win * 16384 + head * 32;
  {
    int kk = tid >> 2, db = (tid & 3) * 8;
    s16x8 kv = *(const s16x8*)(Kb + base + (size_t)kk * 256 + db);
    *(s16x8*)&Ks[kk * 72 + db] = kv;
    s16x8 vv = *(const s16x8*)(V + base + (size_t)kk * 256 + db);
    #pragma unroll
    for (int i = 0; i < 8; ++i) VT[(db + i) * 72 + kk] = vv[i];
  }
  bf16x8 aq = *(const bf16x8*)(Q + base + (size_t)(w * 16 + l15) * 256 + hi * 8);
  __syncthreads();
  f32x4 zero = {0.f, 0.f, 0.f, 0.f};
  f32x4 s[4];
  #pragma unroll
  for (int t = 0; t < 4; ++t) {
    bf16x8 bk = *(const bf16x8*)&Ks[(t * 16 + l15) * 72 + hi * 8];
    s[t] = mfma16(aq, bk, zero);
  }
  float rs[4];
  #pragma unroll
  for (int j = 0; j < 4; ++j) {
    float m = fmaxf(fmaxf(s[0][j], s[1][j]), fmaxf(s[2][j], s[3][j]));
    #pragma unroll
    for (int mk = 1; mk < 16; mk <<= 1) m = fmaxf(m, __shfl_xor(m, mk));
    float sum = 0.f;
    #pragma unroll
    for (int t = 0; t < 4; ++t) { float p = __expf(s[t][j] - m); s[t][j] = p; sum += p; }
    #pragma unroll
    for (int mk = 1; mk < 16; mk <<= 1) sum += __shfl_xor(sum, mk);
    rs[j] = 1.f / sum;
  }
  #pragma unroll
  for (int t = 0; t < 4; ++t)
    #pragma unroll
    for (int j = 0; j < 4; ++j)
      Ps[(w * 16 + hi4 + j) * 72 + t * 16 + l15] = f2bf(s[t][j]);
  __syncthreads();
  f32x4 o[2] = {{0.f,0.f,0.f,0.f}, {0.f,0.f,0.f,0.f}};
  #pragma unroll
  for (int ks = 0; ks < 2; ++ks) {
    bf16x8 ap = *(const bf16x8*)&Ps[(w * 16 + l15) * 72 + ks * 32 + hi * 8];
    #pragma unroll
    for (int dt = 0; dt < 2; ++dt) {
      bf16x8 bv = *(const bf16x8*)&VT[(dt * 16 + l15) * 72 + ks * 32 + hi * 8];
      o[dt] = mfma16(ap, bv, o[dt]);
    }
  }
  #pragma unroll
  for (int dt = 0; dt < 2; ++dt)
    #pragma unroll
    for (int j = 0; j < 4; ++j)
      O[(size_t)(win * 64 + w * 16 + hi4 + j) * 256 + head * 32 + dt * 16 + l15] =
          f2bf(o[dt][j] * rs[j]);
}

// ---------------- proj + residual + LN2: counted-vmcnt staged weights ----------------
__global__ __launch_bounds__(256, 2) void k_proj(
    const short* __restrict__ ao, const short* __restrict__ WprojT,
    const float* __restrict__ pb, const float* __restrict__ x,
    short* __restrict__ y2, short* __restrict__ hresb,
    const float* __restrict__ g2, const float* __restrict__ b2, int chunk_off)
{
  __shared__ __align__(16) short As[64 * 256];      // 32 KB
  __shared__ __align__(16) short Ws[2][256 * 32];   // 2 x 16 KB
  __shared__ float redS[64 * 4];
  __shared__ float redQ[64 * 4];
  const int tid = threadIdx.x, lane = tid & 63, w = tid >> 6;
  const int l15 = lane & 15, hi = lane >> 4, hi4 = hi * 4;
  const int bm0 = blockIdx.x * 64;
  stageW<4>(WprojT, 256, 0, &Ws[0][0], w, lane);    // seq0
  {
    int r2 = lane >> 5, c8 = lane & 31;
    #pragma unroll
    for (int i = 0; i < 8; ++i) {
      int seg = w * 8 + i;
      int row = seg * 2 + r2;
      gload16(ao + (size_t)(bm0 + row) * 256 + ((c8 ^ (row & 7)) * 8), As + seg * 512);
    }
  }
  int cur = 0;
  f32x4 acc[4][4] = {};
  for (int s = 0; s < 8; ++s) {
    stageW<4>(WprojT, 256, ((s + 1) & 7) * 32, &Ws[cur ^ 1][0], w, lane);
    VMCNT(4);     // my As + seq_s landed; only the 4 new loads outstanding
    BAR;          // B1
    bf16x8 af[4], bfr[4];
    #pragma unroll
    for (int m = 0; m < 4; ++m) {
      int row = m * 16 + l15;
      af[m] = *(const bf16x8*)(As + row * 256 + (((s * 4 + hi) ^ (row & 7)) << 3));
    }
    #pragma unroll
    for (int n = 0; n < 4; ++n) {
      int rc = w * 64 + n * 16 + l15;
      bfr[n] = *(const bf16x8*)(&Ws[cur][0] + rc * 32 + ((hi ^ ((rc ^ (rc >> 2)) & 3)) << 3));
    }
    __builtin_amdgcn_s_setprio(1);
    #pragma unroll
    for (int m = 0; m < 4; ++m)
      #pragma unroll
      for (int n = 0; n < 4; ++n) acc[m][n] = mfma16(af[m], bfr[n], acc[m][n]);
    __builtin_amdgcn_s_setprio(0);
    LGKM0;
    BAR;          // B2
    cur ^= 1;
  }
  // epilogue: + bias + x residual (window->spatial), LN2 stats over 256 cols
  int srow[4][4];
  #pragma unroll
  for (int m = 0; m < 4; ++m)
    #pragma unroll
    for (int j = 0; j < 4; ++j) {
      int wrow = chunk_off + bm0 + m * 16 + hi4 + j;
      int bb = wrow >> 12, rem = wrow & 4095, win = rem >> 6, tok = rem & 63;
      int rsp = (tok >> 3) * 8 + (win >> 3);
      int csp = (tok & 7) * 8 + (win & 7);
      srow[m][j] = bb * 4096 + rsp * 64 + csp;
    }
  float s1[4][4] = {}, s2[4][4] = {};
  #pragma unroll
  for (int m = 0; m < 4; ++m)
    #pragma unroll
    for (int n = 0; n < 4; ++n) {
      int col = w * 64 + n * 16 + l15;
      float bia = pb[col];
      #pragma unroll
      for (int j = 0; j < 4; ++j) {
        float val = acc[m][n][j] + bia + x[(size_t)srow[m][j] * 256 + col];
        acc[m][n][j] = val;
        s1[m][j] += val; s2[m][j] += val * val;
      }
    }
  #pragma unroll
  for (int m = 0; m < 4; ++m)
    #pragma unroll
    for (int j = 0; j < 4; ++j) {
      float a = s1[m][j], bq = s2[m][j];
      #pragma unroll
      for (int mk = 1; mk < 16; mk <<= 1) { a += __shfl_xor(a, mk); bq += __shfl_xor(bq, mk); }
      s1[m][j] = a; s2[m][j] = bq;
    }
  if (l15 == 0) {
    #pragma unroll
    for (int m = 0; m < 4; ++m)
      #pragma unroll
      for (int j = 0; j < 4; ++j) {
        int rl = m * 16 + hi4 + j;
        redS[rl * 4 + w] = s1[m][j];
        redQ[rl * 4 + w] = s2[m][j];
      }
  }
  __syncthreads();
  #pragma unroll
  for (int m = 0; m < 4; ++m)
    #pragma unroll
    for (int j = 0; j < 4; ++j) {
      int rl = m * 16 + hi4 + j;
      float S = redS[rl * 4] + redS[rl * 4 + 1] + redS[rl * 4 + 2] + redS[rl * 4 + 3];
      float Qs = redQ[rl * 4] + redQ[rl * 4 + 1] + redQ[rl * 4 + 2] + redQ[rl * 4 + 3];
      float mean = S * (1.f / 256.f);
      float var  = Qs * (1.f / 256.f) - mean * mean;
      float rstd = rsqrtf(var + 1e-5f);
      int lrow = srow[m][j] - chunk_off;
      #pragma unroll
      for (int n = 0; n < 4; ++n) {
        int col = w * 64 + n * 16 + l15;
        float val = acc[m][n][j];
        hresb[(size_t)lrow * 256 + col] = f2bf(val);
        y2[(size_t)lrow * 256 + col] = f2bf((val - mean) * rstd * g2[col] + b2[col]);
      }
    }
}

// ---------------- fused MLP v5: counted-vmcnt 2-barrier schedule ----------------
// 512 thr / 8 waves (2M x 4N), M=128. LDS: As 64K | Ws 2x16K | hs 32K = 128K.
__global__ __launch_bounds__(512, 2) void k_mlp(
    const short* __restrict__ y2, const short* __restrict__ hres,
    const short* __restrict__ W1T, const float* __restrict__ b1,
    const short* __restrict__ W2T, const float* __restrict__ b2,
    float* __restrict__ outp)
{
  extern __shared__ __align__(16) char dsm[];
  short* As = (short*)dsm;                   // [128][256] swizzled
  short* Wb = (short*)(dsm + 65536);         // 2 x 16 KB
  short* hs = (short*)(dsm + 98304);         // [128][128] swizzled (16-slot)
  const int tid = threadIdx.x, lane = tid & 63, w = tid >> 6;
  const int l15 = lane & 15, hi = lane >> 4, hi4 = hi * 4;
  const int wm = w >> 2, wn = w & 3;
  const int bm0 = blockIdx.x * 128;

  auto stage_seq = [&](int seq, short* dst) {   // seq in [0,64), wraps
    int hc = (seq >> 3) & 7, s = seq & 7;
    if (s < 4) {            // W1 panel-step: [128 hcol][64 k], 8-slot swizzle
      #pragma unroll
      for (int i = 0; i < 2; ++i) {
        int idx = (w * 2 + i) * 64 + lane;
        int row = idx >> 3, slot = idx & 7;
        gload16(W1T + (size_t)(hc * 128 + row) * 256 + s * 64 + (slot ^ (row & 7)) * 8,
                dst + (w * 2 + i) * 512);
      }
    } else {                // W2 panel-step: [256 outcol][32 k], 4-slot swizzle
      #pragma unroll
      for (int i = 0; i < 2; ++i) {
        int idx = (w * 2 + i) * 64 + lane;
        int row = idx >> 2, slot = idx & 3;
        gload16(W2T + (size_t)row * 1024 + hc * 128 + (s - 4) * 32 +
                    (slot ^ ((row ^ (row >> 2)) & 3)) * 8,
                dst + (w * 2 + i) * 512);
      }
    }
  };

  // prologue: stage As (64 KB) + seq0
  #pragma unroll
  for (int i = 0; i < 8; ++i) {
    int idx = (w * 8 + i) * 64 + lane;
    int row = idx >> 5, c = idx & 31;
    int sc = (c & 24) | ((c & 7) ^ (row & 7));
    gload16(y2 + (size_t)(bm0 + row) * 256 + sc * 8, As + (w * 8 + i) * 512);
  }
  stage_seq(0, Wb);
  f32x4 oacc[4][4] = {};
  int cur = 0;
  for (int hc = 0; hc < 8; ++hc) {
    f32x4 acc1[4][2] = {};
    #pragma unroll
    for (int s = 0; s < 4; ++s) {      // ---- P1 (seq = hc*8+s)
      stage_seq((hc * 8 + s + 1) & 63, Wb + (cur ^ 1) * 8192);
      VMCNT(2);
      BAR;                             // B1: all waves' current panel landed
      const short* Wc = Wb + cur * 8192;
      bf16x8 af[2][4], wf[2][2];
      #pragma unroll
      for (int q = 0; q < 2; ++q) {
        int kk = s * 2 + q;
        #pragma unroll
        for (int m = 0; m < 4; ++m) {
          int row = wm * 64 + m * 16 + l15;
          af[q][m] = *(const bf16x8*)(As + row * 256 + (((kk * 4 + hi) ^ (row & 7)) << 3));
        }
        #pragma unroll
        for (int n2 = 0; n2 < 2; ++n2) {
          int rc = wn * 32 + n2 * 16 + l15;
          wf[q][n2] = *(const bf16x8*)(Wc + rc * 64 + (((q * 4 + hi) ^ (rc & 7)) << 3));
        }
      }
      __builtin_amdgcn_s_setprio(1);
      #pragma unroll
      for (int q = 0; q < 2; ++q)
        #pragma unroll
        for (int m = 0; m < 4; ++m) {
          acc1[m][0] = mfma16(wf[q][0], af[q][m], acc1[m][0]);   // D[hcol][xrow]
          acc1[m][1] = mfma16(wf[q][1], af[q][m], acc1[m][1]);
        }
      __builtin_amdgcn_s_setprio(0);
      LGKM0;
      BAR;                             // B2
      cur ^= 1;
    }
    // GELU -> hs
    #pragma unroll
    for (int m = 0; m < 4; ++m)
      #pragma unroll
      for (int n2 = 0; n2 < 2; ++n2) {
        int xrow = wm * 64 + m * 16 + l15;
        int hcolb = wn * 32 + n2 * 16 + hi4;
        float4 bbv = *(const float4*)(b1 + hc * 128 + hcolb);
        float bj[4] = {bbv.x, bbv.y, bbv.z, bbv.w};
        s16x4 o;
        #pragma unroll
        for (int j = 0; j < 4; ++j) {
          float vv = acc1[m][n2][j] + bj[j];
          float z = vv + 0.044715f * vv * vv * vv;
          o[j] = f2bf(vv / (1.f + __expf(-1.5957691216057308f * z)));
        }
        int chunk = hcolb >> 3;
        *(s16x4*)(hs + xrow * 128 + ((chunk ^ (xrow & 15)) << 3) + (hi & 1) * 4) = o;
      }
    LGKM0;
    BAR;                               // B3: hs visible
    #pragma unroll
    for (int s = 0; s < 4; ++s) {      // ---- P2 (seq = hc*8+4+s)
      stage_seq((hc * 8 + 4 + s + 1) & 63, Wb + (cur ^ 1) * 8192);
      VMCNT(2);
      BAR;                             // B1
      const short* Wc = Wb + cur * 8192;
      bf16x8 hf[4], w2f[4];
      #pragma unroll
      for (int m = 0; m < 4; ++m) {
        int xr = wm * 64 + m * 16 + l15;
        hf[m] = *(const bf16x8*)(hs + xr * 128 + (((s * 4 + hi) ^ (xr & 15)) << 3));
      }
      #pragma unroll
      for (int n = 0; n < 4; ++n) {
        int rc = wn * 64 + n * 16 + l15;
        w2f[n] = *(const bf16x8*)(Wc + rc * 32 + ((hi ^ ((rc ^ (rc >> 2)) & 3)) << 3));
      }
      __builtin_amdgcn_s_setprio(1);
      #pragma unroll
      for (int m = 0; m < 4; ++m)
        #pragma unroll
        for (int n = 0; n < 4; ++n)
          oacc[m][n] = mfma16(w2f[n], hf[m], oacc[m][n]);        // D[outcol][xrow]
      __builtin_amdgcn_s_setprio(0);
      LGKM0;
      BAR;                             // B2
      cur ^= 1;
    }
  }
  // epilogue
  #pragma unroll
  for (int m = 0; m < 4; ++m)
    #pragma unroll
    for (int n = 0; n < 4; ++n) {
      size_t row = (size_t)bm0 + wm * 64 + m * 16 + l15;
      int colb = wn * 64 + n * 16 + hi4;
      float4 bbv = *(const float4*)(b2 + colb);
      s16x4 hr = *(const s16x4*)(hres + row * 256 + colb);
      float4 ov;
      ov.x = oacc[m][n][0] + bbv.x + bf2f(hr[0]);
      ov.y = oacc[m][n][1] + bbv.y + bf2f(hr[1]);
      ov.z = oacc[m][n][2] + bbv.z + bf2f(hr[2]);
      ov.w = oacc[m][n][3] + bbv.w + bf2f(hr[3]);
      *(float4*)(outp + row * 256 + colb) = ov;
    }
}

// ---------------- host ----------------
extern "C" void kernel_launch(void* const* d_in, const int* in_sizes, int n_in,
                              void* d_out, int out_size, void* d_ws, size_t ws_size,
                              hipStream_t stream) {
  const float* x     = (const float*)d_in[0];
  const float* ln1g  = (const float*)d_in[1];
  const float* ln1b  = (const float*)d_in[2];
  const float* qkvw  = (const float*)d_in[3];
  const float* qkvb  = (const float*)d_in[4];
  const float* projw = (const float*)d_in[5];
  const float* projb = (const float*)d_in[6];
  const float* ln2g  = (const float*)d_in[7];
  const float* ln2b  = (const float*)d_in[8];
  const float* w1    = (const float*)d_in[9];
  const float* b1    = (const float*)d_in[10];
  const float* w2    = (const float*)d_in[11];
  const float* b2    = (const float*)d_in[12];
  float* out = (float*)d_out;
  char* ws = (char*)d_ws;

  static int mlp_attr_set = 0;
  if (!mlp_attr_set) {
    hipFuncSetAttribute((const void*)k_mlp,
                        hipFuncAttributeMaxDynamicSharedMemorySize, 131072);
    mlp_attr_set = 1;
  }

  const size_t MTOT = 131072;
  int nchunk;
  if (ws_size >= 4ull * MTOT * 512 + (2u << 20)) nchunk = 1;
  else if (ws_size >= 4ull * (MTOT / 2) * 512 + (2u << 20)) nchunk = 2;
  else nchunk = 4;
  const size_t M = MTOT / nchunk;
  const int nwin = (int)(M / 64);

  short* qkv = (short*)ws;
  short* y2b = (short*)ws;
  short* hrb = (short*)ws + M * 256;
  short* aob = (short*)ws + 3 * M * 256;
  char*  wreg = ws + 4ull * M * 512;
  short* WqkvT  = (short*)wreg;                      // 393,216 B
  short* WprojT = (short*)(wreg + 393216);           // 131,072 B
  short* W1T    = (short*)(wreg + 524288);           // 524,288 B
  short* W2T    = (short*)(wreg + 1048576);          // 524,288 B
  float* qkvbp  = (float*)(wreg + 1572864);          // 3,072 B

  k_prep_qkv<<<768, 256, 0, stream>>>(qkvw, qkvb, WqkvT, qkvbp);
  k_transpose<<<256, 256, 0, stream>>>(projw, WprojT, 256, 256);
  k_transpose<<<1024, 256, 0, stream>>>(w1, W1T, 256, 1024);
  k_transpose<<<1024, 256, 0, stream>>>(w2, W2T, 1024, 256);

  for (int c = 0; c < nchunk; ++c) {
    k_qkvln<<<nwin, 256, 0, stream>>>(x, ln1g, ln1b, WqkvT, qkvbp, qkv,
                                      c * nwin, (int)M);
    k_attn<<<nwin * 8, 256, 0, stream>>>(qkv, qkv + M * 256, qkv + 2 * M * 256, aob);
    k_proj<<<nwin, 256, 0, stream>>>(aob, WprojT, projb, x, y2b, hrb,
                                     ln2g, ln2b, (int)(c * M));
    k_mlp<<<(int)(M / 128), 512, 131072, stream>>>(y2b, hrb, W1T, b1, W2T, b2,
                                                   out + (size_t)c * M * 256);
  }
}